// Round 1
// baseline (323.129 us; speedup 1.0000x reference)
//
#include <hip/hip_runtime.h>

#define N_USERS   200000
#define N_ITEMS   100000
#define DIM       64
#define N_NODES   300000
#define N_EDGES   1200000
#define BIN_SHIFT 8
#define NBINS     1172            // ceil(300000/256)
#define CHUNK     4096
#define NCHUNKS   293             // ceil(1200000/4096)
#define BIN_CAP   2048            // mean edges/bin = 1024 -> huge margin

// ---- bf16 helpers (manual RNE; no NaN inputs here) ------------------------
__device__ __forceinline__ unsigned short f2b(float f) {
    unsigned u = __float_as_uint(f);
    u += 0x7FFFu + ((u >> 16) & 1u);
    return (unsigned short)(u >> 16);
}
__device__ __forceinline__ float blo(unsigned w) { return __uint_as_float(w << 16); }
__device__ __forceinline__ float bhi(unsigned w) { return __uint_as_float(w & 0xFFFF0000u); }
__device__ __forceinline__ unsigned packbf(float lo, float hi) {
    return (unsigned)f2b(lo) | ((unsigned)f2b(hi) << 16);
}

// ---------------------------------------------------------------------------
// Phase A1: per-chunk histogram over bins. int4 loads, 4 outstanding before use.
__global__ __launch_bounds__(256) void histA_kernel(const int* __restrict__ row,
                                                    int* __restrict__ histG,
                                                    int* __restrict__ binTot) {
    __shared__ int h[NBINS];
    for (int i = threadIdx.x; i < NBINS; i += 256) h[i] = 0;
    __syncthreads();
    const int4* row4 = (const int4*)row;
    int base4 = blockIdx.x * (CHUNK / 4);                 // N_EDGES % 4 == 0
    int end4  = min(base4 + CHUNK / 4, N_EDGES / 4);
    int i0 = base4 + threadIdx.x;
    int i1 = i0 + 256, i2 = i0 + 512, i3 = i0 + 768;
    int4 r0, r1, r2, r3;
    bool v0 = i0 < end4, v1 = i1 < end4, v2 = i2 < end4, v3 = i3 < end4;
    if (v0) r0 = row4[i0];
    if (v1) r1 = row4[i1];
    if (v2) r2 = row4[i2];
    if (v3) r3 = row4[i3];
    if (v0) { atomicAdd(&h[r0.x >> BIN_SHIFT], 1); atomicAdd(&h[r0.y >> BIN_SHIFT], 1);
              atomicAdd(&h[r0.z >> BIN_SHIFT], 1); atomicAdd(&h[r0.w >> BIN_SHIFT], 1); }
    if (v1) { atomicAdd(&h[r1.x >> BIN_SHIFT], 1); atomicAdd(&h[r1.y >> BIN_SHIFT], 1);
              atomicAdd(&h[r1.z >> BIN_SHIFT], 1); atomicAdd(&h[r1.w >> BIN_SHIFT], 1); }
    if (v2) { atomicAdd(&h[r2.x >> BIN_SHIFT], 1); atomicAdd(&h[r2.y >> BIN_SHIFT], 1);
              atomicAdd(&h[r2.z >> BIN_SHIFT], 1); atomicAdd(&h[r2.w >> BIN_SHIFT], 1); }
    if (v3) { atomicAdd(&h[r3.x >> BIN_SHIFT], 1); atomicAdd(&h[r3.y >> BIN_SHIFT], 1);
              atomicAdd(&h[r3.z >> BIN_SHIFT], 1); atomicAdd(&h[r3.w >> BIN_SHIFT], 1); }
    __syncthreads();
    for (int i = threadIdx.x; i < NBINS; i += 256) {
        int v = h[i];
        histG[blockIdx.x * NBINS + i] = v;
        if (v) atomicAdd(&binTot[i], v);
    }
}

// histG[chunk][bin] -> global start offsets: one 64-lane wave per bin.
// Bin prefix (exclusive scan of binTot) computed in-block by direct reduction
// over the 4.7 KB binTot array (L2-resident) -- replaces the serial scanB
// kernel entirely. Then shfl-based scan over the 293 chunks.
__global__ __launch_bounds__(64) void rewrite_kernel(int* __restrict__ histG,
                                                     const int* __restrict__ binTot,
                                                     int* __restrict__ binStart) {
    int b    = blockIdx.x;
    int lane = threadIdx.x;
    // exclusive prefix: sum binTot[0..b-1]
    int pre = 0;
    for (int i = lane; i < b; i += 64) pre += binTot[i];
#pragma unroll
    for (int off = 1; off < 64; off <<= 1) pre += __shfl_xor(pre, off, 64);
    if (lane == 0) binStart[b] = pre;
    if (b == 0 && lane == 0) binStart[NBINS] = N_EDGES;
    int carry = pre;
    for (int base = 0; base < NCHUNKS; base += 64) {
        int idx = base + lane;
        int v = (idx < NCHUNKS) ? histG[idx * NBINS + b] : 0;
        int incl = v;
        for (int off = 1; off < 64; off <<= 1) {
            int t = __shfl_up(incl, off, 64);
            if (lane >= off) incl += t;
        }
        if (idx < NCHUNKS) histG[idx * NBINS + b] = carry + incl - v;
        carry += __shfl(incl, 63, 64);
    }
}

// Phase A2: place packed (col<<8 | row&255) into bin-major tmp.
// int4 loads of row+col, 8 outstanding before use; LDS cursors.
__global__ __launch_bounds__(256) void placeA_kernel(const int* __restrict__ row,
                                                     const int* __restrict__ col,
                                                     const int* __restrict__ histG,
                                                     int* __restrict__ tmp) {
    __shared__ int ofs[NBINS];
    for (int i = threadIdx.x; i < NBINS; i += 256)
        ofs[i] = histG[blockIdx.x * NBINS + i];
    __syncthreads();
    const int4* row4 = (const int4*)row;
    const int4* col4 = (const int4*)col;
    int base4 = blockIdx.x * (CHUNK / 4);
    int end4  = min(base4 + CHUNK / 4, N_EDGES / 4);
    int i0 = base4 + threadIdx.x;
    int i1 = i0 + 256, i2 = i0 + 512, i3 = i0 + 768;
    int4 r0, r1, r2, r3, c0, c1, c2, c3;
    bool v0 = i0 < end4, v1 = i1 < end4, v2 = i2 < end4, v3 = i3 < end4;
    if (v0) { r0 = row4[i0]; c0 = col4[i0]; }
    if (v1) { r1 = row4[i1]; c1 = col4[i1]; }
    if (v2) { r2 = row4[i2]; c2 = col4[i2]; }
    if (v3) { r3 = row4[i3]; c3 = col4[i3]; }
    auto put = [&](int r, int c) {
        int pos = atomicAdd(&ofs[r >> BIN_SHIFT], 1);
        tmp[pos] = (c << BIN_SHIFT) | (r & 255);
    };
    if (v0) { put(r0.x, c0.x); put(r0.y, c0.y); put(r0.z, c0.z); put(r0.w, c0.w); }
    if (v1) { put(r1.x, c1.x); put(r1.y, c1.y); put(r1.z, c1.z); put(r1.w, c1.w); }
    if (v2) { put(r2.x, c2.x); put(r2.y, c2.y); put(r2.z, c2.z); put(r2.w, c2.w); }
    if (v3) { put(r3.x, c3.x); put(r3.y, c3.y); put(r3.z, c3.z); put(r3.w, c3.w); }
}

// Phase B: one workgroup per bin; LDS counting sort by (row&255); emits
// col_e coalesced + row_ptr + dis/invd + FUSED conv (g0 = x*dis bf16) for
// its contiguous 256-node range.
__global__ __launch_bounds__(256) void binsort_kernel(const int* __restrict__ tmp,
                                                      const int* __restrict__ binStart,
                                                      int* __restrict__ col_e,
                                                      int* __restrict__ row_ptr,
                                                      float* __restrict__ dis,
                                                      float* __restrict__ invd,
                                                      const float* __restrict__ ue,
                                                      const float* __restrict__ ie,
                                                      unsigned short* __restrict__ g0) {
    __shared__ int hist[256];
    __shared__ int lofs[256];
    __shared__ int colsOut[BIN_CAP];
    int b  = blockIdx.x;
    int jb = binStart[b], je = binStart[b + 1];
    int n  = je - jb;
    hist[threadIdx.x] = 0;
    __syncthreads();
    int ed[8], rk[8];
    int cnt = 0;
    for (int i = threadIdx.x; i < n && cnt < 8; i += 256) {
        int rc = tmp[jb + i];
        ed[cnt] = rc;
        rk[cnt] = atomicAdd(&hist[rc & 255], 1);
        cnt++;
    }
    __syncthreads();
    int deg = hist[threadIdx.x];
    lofs[threadIdx.x] = deg;
    __syncthreads();
    for (int off = 1; off < 256; off <<= 1) {
        int t = (threadIdx.x >= off) ? lofs[threadIdx.x - off] : 0;
        __syncthreads();
        lofs[threadIdx.x] += t;
        __syncthreads();
    }
    int myEx = lofs[threadIdx.x] - deg;
    int node = (b << BIN_SHIFT) + threadIdx.x;
    if (node < N_NODES) {
        row_ptr[node] = jb + myEx;
        float fd = (float)deg;
        dis[node]  = (deg > 0) ? rsqrtf(fd) : 0.0f;
        invd[node] = (deg > 0) ? sqrtf(fd)  : 0.0f;
    }
    if (b == 0 && threadIdx.x == 0) row_ptr[N_NODES] = N_EDGES;
    lofs[threadIdx.x] = myEx;
    __syncthreads();
    for (int k = 0; k < cnt; ++k)
        colsOut[lofs[ed[k] & 255] + rk[k]] = ((unsigned)ed[k]) >> BIN_SHIFT;
    __syncthreads();
    for (int i = threadIdx.x; i < n; i += 256)
        col_e[jb + i] = colsOut[i];

    // ---- fused conv: g0 rows for nodes [b*256, b*256+256), 8 lanes/node ----
    int q = threadIdx.x & 7;
    for (int pass = 0; pass < 8; ++pass) {
        int nl = pass * 32 + (threadIdx.x >> 3);
        int nd = (b << BIN_SHIFT) + nl;
        if (nd >= N_NODES) break;
        int dg = hist[nl];
        float w = (dg > 0) ? rsqrtf((float)dg) : 0.0f;
        const float* src = (nd < N_USERS) ? (ue + nd * DIM)
                                          : (ie + (nd - N_USERS) * DIM);
        float4 x0 = ((const float4*)src)[2 * q];
        float4 x1 = ((const float4*)src)[2 * q + 1];
        uint4 o;
        o.x = packbf(w * x0.x, w * x0.y);
        o.y = packbf(w * x0.z, w * x0.w);
        o.z = packbf(w * x1.x, w * x1.y);
        o.w = packbf(w * x1.z, w * x1.w);
        ((uint4*)(g0 + nd * DIM))[q] = o;
    }
}

// ---------------------------------------------------------------------------
// Atomic-free bf16 pull: 8 lanes per PAIR of consecutive nodes (nA = 2*grp,
// nB = nA+1). Their CSR ranges are adjacent; up to 8 col loads + 8 uint4
// gathers are issued before any consumption -> 2x memory-level parallelism
// per wave vs the 1-node/group version.
// g_{l+1}[r] = dis_r^2 * sum g_l[c].
// FINAL: out = 0.25*(x + (g1+g2)*sqrt(deg) + dis*sum g2[c])
template <bool FINAL>
__global__ __launch_bounds__(256) void pull_kernel(
        const unsigned short* __restrict__ g_in,
        const int* __restrict__ row_ptr, const int* __restrict__ col_e,
        const float* __restrict__ dis, const float* __restrict__ invd,
        const float* __restrict__ ue, const float* __restrict__ ie,
        const unsigned short* __restrict__ gA,
        const unsigned short* __restrict__ gB,
        unsigned short* __restrict__ g_out,
        float* __restrict__ out) {
    int gid  = blockIdx.x * blockDim.x + threadIdx.x;
    int grp  = gid >> 3;
    int q    = gid & 7;
    int nA   = grp << 1;           // N_NODES is even -> nB always valid
    if (nA >= N_NODES) return;
    int nB   = nA + 1;
    int jA   = row_ptr[nA];
    int m    = row_ptr[nA + 1];
    int jeB  = row_ptr[nA + 2];
    int jeA  = m;
    int jB   = m;
    const uint4* gin4 = (const uint4*)g_in;   // row = 8 uint4

    float accA[8], accB[8];
#pragma unroll
    for (int k = 0; k < 8; ++k) { accA[k] = 0.f; accB[k] = 0.f; }

    auto accumA = [&](uint4 u) {
        accA[0] += blo(u.x); accA[1] += bhi(u.x);
        accA[2] += blo(u.y); accA[3] += bhi(u.y);
        accA[4] += blo(u.z); accA[5] += bhi(u.z);
        accA[6] += blo(u.w); accA[7] += bhi(u.w);
    };
    auto accumB = [&](uint4 u) {
        accB[0] += blo(u.x); accB[1] += bhi(u.x);
        accB[2] += blo(u.y); accB[3] += bhi(u.y);
        accB[4] += blo(u.z); accB[5] += bhi(u.z);
        accB[6] += blo(u.w); accB[7] += bhi(u.w);
    };

    while (jA < jeA || jB < jeB) {
        int ra = jeA - jA;
        int rb = jeB - jB;
        bool a0 = ra > 0, a1 = ra > 1, a2 = ra > 2, a3 = ra > 3;
        bool b0 = rb > 0, b1 = rb > 1, b2 = rb > 2, b3 = rb > 3;
        int cA0, cA1, cA2, cA3, cB0, cB1, cB2, cB3;
        if (a0) cA0 = col_e[jA];
        if (a1) cA1 = col_e[jA + 1];
        if (a2) cA2 = col_e[jA + 2];
        if (a3) cA3 = col_e[jA + 3];
        if (b0) cB0 = col_e[jB];
        if (b1) cB1 = col_e[jB + 1];
        if (b2) cB2 = col_e[jB + 2];
        if (b3) cB3 = col_e[jB + 3];
        uint4 uA0, uA1, uA2, uA3, uB0, uB1, uB2, uB3;
        if (a0) uA0 = gin4[cA0 * 8 + q];
        if (a1) uA1 = gin4[cA1 * 8 + q];
        if (a2) uA2 = gin4[cA2 * 8 + q];
        if (a3) uA3 = gin4[cA3 * 8 + q];
        if (b0) uB0 = gin4[cB0 * 8 + q];
        if (b1) uB1 = gin4[cB1 * 8 + q];
        if (b2) uB2 = gin4[cB2 * 8 + q];
        if (b3) uB3 = gin4[cB3 * 8 + q];
        if (a0) accumA(uA0);
        if (a1) accumA(uA1);
        if (a2) accumA(uA2);
        if (a3) accumA(uA3);
        if (b0) accumB(uB0);
        if (b1) accumB(uB1);
        if (b2) accumB(uB2);
        if (b3) accumB(uB3);
        jA += min(ra, 4);
        jB += min(rb, 4);
    }

    float drA = dis[nA];
    float drB = dis[nB];
    if (!FINAL) {
        float sA = drA * drA;
        float sB = drB * drB;
        uint4 oA, oB;
        oA.x = packbf(sA * accA[0], sA * accA[1]);
        oA.y = packbf(sA * accA[2], sA * accA[3]);
        oA.z = packbf(sA * accA[4], sA * accA[5]);
        oA.w = packbf(sA * accA[6], sA * accA[7]);
        oB.x = packbf(sB * accB[0], sB * accB[1]);
        oB.y = packbf(sB * accB[2], sB * accB[3]);
        oB.z = packbf(sB * accB[4], sB * accB[5]);
        oB.w = packbf(sB * accB[6], sB * accB[7]);
        ((uint4*)(g_out + nA * DIM))[q] = oA;
        ((uint4*)(g_out + nB * DIM))[q] = oB;
    } else {
        // node A
        {
            float iv = invd[nA];
            const float* xs = (nA < N_USERS) ? (ue + nA * DIM)
                                             : (ie + (nA - N_USERS) * DIM);
            float4 x0 = ((const float4*)xs)[2 * q];
            float4 x1 = ((const float4*)xs)[2 * q + 1];
            uint4 a = ((const uint4*)gA)[nA * 8 + q];
            uint4 b = ((const uint4*)gB)[nA * 8 + q];
            float4 o0, o1;
            o0.x = 0.25f * (x0.x + (blo(a.x) + blo(b.x)) * iv + drA * accA[0]);
            o0.y = 0.25f * (x0.y + (bhi(a.x) + bhi(b.x)) * iv + drA * accA[1]);
            o0.z = 0.25f * (x0.z + (blo(a.y) + blo(b.y)) * iv + drA * accA[2]);
            o0.w = 0.25f * (x0.w + (bhi(a.y) + bhi(b.y)) * iv + drA * accA[3]);
            o1.x = 0.25f * (x1.x + (blo(a.z) + blo(b.z)) * iv + drA * accA[4]);
            o1.y = 0.25f * (x1.y + (bhi(a.z) + bhi(b.z)) * iv + drA * accA[5]);
            o1.z = 0.25f * (x1.z + (blo(a.w) + blo(b.w)) * iv + drA * accA[6]);
            o1.w = 0.25f * (x1.w + (bhi(a.w) + bhi(b.w)) * iv + drA * accA[7]);
            ((float4*)out)[nA * 16 + 2 * q]     = o0;
            ((float4*)out)[nA * 16 + 2 * q + 1] = o1;
        }
        // node B
        {
            float iv = invd[nB];
            const float* xs = (nB < N_USERS) ? (ue + nB * DIM)
                                             : (ie + (nB - N_USERS) * DIM);
            float4 x0 = ((const float4*)xs)[2 * q];
            float4 x1 = ((const float4*)xs)[2 * q + 1];
            uint4 a = ((const uint4*)gA)[nB * 8 + q];
            uint4 b = ((const uint4*)gB)[nB * 8 + q];
            float4 o0, o1;
            o0.x = 0.25f * (x0.x + (blo(a.x) + blo(b.x)) * iv + drB * accB[0]);
            o0.y = 0.25f * (x0.y + (bhi(a.x) + bhi(b.x)) * iv + drB * accB[1]);
            o0.z = 0.25f * (x0.z + (blo(a.y) + blo(b.y)) * iv + drB * accB[2]);
            o0.w = 0.25f * (x0.w + (bhi(a.y) + bhi(b.y)) * iv + drB * accB[3]);
            o1.x = 0.25f * (x1.x + (blo(a.z) + blo(b.z)) * iv + drB * accB[4]);
            o1.y = 0.25f * (x1.y + (bhi(a.z) + bhi(b.z)) * iv + drB * accB[5]);
            o1.z = 0.25f * (x1.z + (blo(a.w) + blo(b.w)) * iv + drB * accB[6]);
            o1.w = 0.25f * (x1.w + (bhi(a.w) + bhi(b.w)) * iv + drB * accB[7]);
            ((float4*)out)[nB * 16 + 2 * q]     = o0;
            ((float4*)out)[nB * 16 + 2 * q + 1] = o1;
        }
    }
}

extern "C" void kernel_launch(void* const* d_in, const int* in_sizes, int n_in,
                              void* d_out, int out_size, void* d_ws, size_t ws_size,
                              hipStream_t stream) {
    const float* ue  = (const float*)d_in[0];
    const float* ie  = (const float*)d_in[1];
    const int*   ei  = (const int*)d_in[2];
    const int*   row = ei;
    const int*   col = ei + N_EDGES;
    float*       out = (float*)d_out;

    // workspace layout (~135 MB)
    size_t gElems = (size_t)N_NODES * DIM;                 // 19.2 M
    unsigned short* g0 = (unsigned short*)d_ws;            // 38.4 MB
    unsigned short* g1 = g0 + gElems;                      // 38.4 MB
    unsigned short* g2 = g1 + gElems;                      // 38.4 MB
    int*   tmp      = (int*)(g2 + gElems);                 // 4.8 MB (packed)
    int*   col_e    = tmp + N_EDGES;                       // 4.8 MB
    int*   row_ptr  = col_e + N_EDGES;                     // 1.2 MB
    float* dis      = (float*)(row_ptr + N_NODES + 1);
    float* invd     = dis + N_NODES;
    int*   histG    = (int*)(invd + N_NODES);              // 293*1172*4 = 1.37 MB
    int*   binTot   = histG + NCHUNKS * NBINS;
    int*   binStart = binTot + NBINS;

    const int B  = 256;
    const int GP = ((N_NODES / 2) * 8 + B - 1) / B;        // 2 nodes per 8-lane group

    // ---- CSR build: LDS counting sort, no global fine-grained scatter ----
    hipMemsetAsync(binTot, 0, (size_t)NBINS * sizeof(int), stream);
    histA_kernel   <<<NCHUNKS, B, 0, stream>>>(row, histG, binTot);
    rewrite_kernel <<<NBINS, 64, 0, stream>>>(histG, binTot, binStart);
    placeA_kernel  <<<NCHUNKS, B, 0, stream>>>(row, col, histG, tmp);
    binsort_kernel <<<NBINS, B, 0, stream>>>(tmp, binStart, col_e, row_ptr, dis, invd,
                                             ue, ie, g0);

    // ---- 3 bf16 pull layers; acc + scale fused into the last epilogue ----
    pull_kernel<false><<<GP, B, 0, stream>>>(g0, row_ptr, col_e, dis, invd,
                                             nullptr, nullptr, nullptr, nullptr, g1, nullptr);
    pull_kernel<false><<<GP, B, 0, stream>>>(g1, row_ptr, col_e, dis, invd,
                                             nullptr, nullptr, nullptr, nullptr, g2, nullptr);
    pull_kernel<true ><<<GP, B, 0, stream>>>(g2, row_ptr, col_e, dis, invd,
                                             ue, ie, g1, g2, nullptr, out);
}